// Round 6
// baseline (62.554 us; speedup 1.0000x reference)
//
#include <hip/hip_runtime.h>

#define EPSLN 1e-5f
#define KMINC 9
#define NBLK  4          // j-split blocks per (b,i)

typedef _Float16 h2 __attribute__((ext_vector_type(2)));
typedef _Float16 h4 __attribute__((ext_vector_type(4)));

#if defined(__has_builtin)
#if __has_builtin(__builtin_amdgcn_fdot2)
#define FDOT2(a,b,c) __builtin_amdgcn_fdot2((a),(b),(c),false)
#endif
#endif
#ifndef FDOT2
#define FDOT2(a,b,c) ((c) + (float)(a)[0]*(float)(b)[0] + (float)(a)[1]*(float)(b)[1])
#endif

__device__ __forceinline__ h2 mk2(float a, float b){
  h2 v; v[0]=(_Float16)a; v[1]=(_Float16)b; return v;
}

__device__ __forceinline__ float wred64(float v){
  #pragma unroll
  for (int m=1;m<64;m<<=1) v += __shfl_xor(v,m,64);
  return v;
}
__device__ __forceinline__ float wred32(float v){
  #pragma unroll
  for (int m=1;m<32;m<<=1) v += __shfl_xor(v,m,64);
  return v;
}

// ---------------- Kernel P: fused msa-LN/attention/node  +  distance/top-k/mask ----------------
// grid = B*L (512), block = 256 (4 waves)
__global__ __launch_bounds__(256) void k_prep(
    const float* __restrict__ msa, const float* __restrict__ seq1hot,
    const float* __restrict__ xyz, const int* __restrict__ idxp,
    const int* __restrict__ topk,
    const float* __restrict__ g_msa, const float* __restrict__ b_msa,
    const float* __restrict__ Wq, const float* __restrict__ bq,
    const float* __restrict__ Wk, const float* __restrict__ bk,
    const float* __restrict__ Wx, const float* __restrict__ bx,
    const float* __restrict__ g_node, const float* __restrict__ b_node,
    float* __restrict__ node, int* __restrict__ cnt, int* __restrict__ jlist)
{
  const int bid = blockIdx.x;          // b*256 + l  (l == i)
  const int b = bid >> 8;
  const int tid = threadIdx.x;
  const int w = tid >> 6, lane = tid & 63;

  __shared__ float mn[32][64];
  __shared__ float qS[64];
  __shared__ float scS[32];
  __shared__ float redS[4][64];
  __shared__ float ssumS[4];
  __shared__ float Dv[256];
  __shared__ int   wsum[4];

  const float gm = g_msa[lane], bm = b_msa[lane];
  for (int nn=w; nn<32; nn+=4){
    float x = msa[(size_t)(((b*32+nn)<<8)+(bid&255))*64 + lane];
    float s = wred64(x), s2 = wred64(x*x);
    float mu = s*(1.f/64.f);
    float var = s2*(1.f/64.f) - mu*mu;
    mn[nn][lane] = (x-mu)*rsqrtf(var+EPSLN)*gm + bm;
  }
  __syncthreads();
  if (w==0){
    float q = bq[lane];
    for (int d=0; d<64; d++) q += mn[0][d]*Wq[d*64+lane];
    qS[lane] = q*0.125f;               // 1/sqrt(64)
  }
  __syncthreads();
  {
    float partial = 0.f;
    for (int e=w*16; e<w*16+16; e++) partial += Wk[lane*64+e]*qS[e];
    redS[w][lane] = partial;
  }
  __syncthreads();
  const float qk = redS[0][lane]+redS[1][lane]+redS[2][lane]+redS[3][lane];
  const float qb = wred64(qS[lane]*bk[lane]);
  for (int nn=w*8; nn<w*8+8; nn++){
    float p = wred64(mn[nn][lane]*qk);
    if (lane==0) scS[nn] = p + qb;
  }
  __syncthreads();
  float mx = -1e30f;
  for (int nn=0; nn<32; nn++) mx = fmaxf(mx, scS[nn]);
  float ps=0.f, pm=0.f;
  for (int nn=w*8; nn<w*8+8; nn++){
    float e = expf(scS[nn]-mx);
    ps += e; pm += e*mn[nn][lane];
  }
  redS[w][lane] = pm;
  if (lane==0) ssumS[w] = ps;
  __syncthreads();
  if (w==0){
    float ssum = ssumS[0]+ssumS[1]+ssumS[2]+ssumS[3];
    qS[lane] = (redS[0][lane]+redS[1][lane]+redS[2][lane]+redS[3][lane]) / ssum;
  }
  __syncthreads();
  if (tid<32){
    float acc = bx[tid];
    for (int k=0;k<64;k++) acc += qS[k]*Wx[k*32+tid];
    const float* s1 = &seq1hot[bid*21];
    for (int k=0;k<21;k++) acc += s1[k]*Wx[(64+k)*32+tid];
    float s = wred32(acc), s2 = wred32(acc*acc);
    float mu = s*(1.f/32.f), var = s2*(1.f/32.f)-mu*mu;
    node[bid*32+tid] = (acc-mu)*rsqrtf(var+EPSLN)*g_node[tid] + b_node[tid];
  }

  // --- Phase 2: distances, exact stable top-k rank, compaction (thread = j) ---
  const int i = bid & 255;
  const int j = tid;
  const float cax = xyz[(bid*3+1)*3+0];
  const float cay = xyz[(bid*3+1)*3+1];
  const float caz = xyz[(bid*3+1)*3+2];
  const int jb = (b<<8)+j;
  float dx = xyz[(jb*3+1)*3+0]-cax;
  float dy = xyz[(jb*3+1)*3+1]-cay;
  float dz = xyz[(jb*3+1)*3+2]-caz;
  float D = sqrtf(dx*dx+dy*dy+dz*dz) + (i==j ? 999.9f : 0.f);
  __syncthreads();
  Dv[j] = D;
  __syncthreads();
  int rank = 0;
  for (int j2=0;j2<256;j2++){
    float v = Dv[j2];
    rank += (v < D || (v == D && j2 < j)) ? 1 : 0;
  }
  int K = topk[0];
  if (K<=0 || K>256){
    float f = ((const float*)topk)[0];
    K = (f>=1.f && f<=256.f) ? (int)f : 64;
  }
  const int sep = abs(idxp[jb] - idxp[bid]);
  const bool m = (rank < K) || (i!=j && sep < KMINC);
  unsigned long long bal = __ballot(m);
  const int l6 = j & 63, wv = j >> 6;
  const int pre = __popcll(bal & ((1ull<<l6)-1ull));
  if (l6==0) wsum[wv] = __popcll(bal);
  __syncthreads();
  int off = 0;
  for (int w2=0;w2<wv;w2++) off += wsum[w2];
  if (m) jlist[bid*256 + off + pre] = j;
  if (j==0) cnt[bid] = wsum[0]+wsum[1]+wsum[2]+wsum[3];
}

// ---------------- Kernel C: gathered pair pipeline, f16 LDS + fdot2 ----------------
// grid = B*L*NBLK (2048), block = 256 = 8 groups of 32; group does 2 j per pass (16 rows)
// All loop-spanning scalars live in LDS (m0bS, bias arrays, jlS) so the 64-VGPR
// allocation has nothing left to spill (r5: 15.5 MB scratch writes at VGPR=64).
__global__ __launch_bounds__(256) void k_main(
    const float* __restrict__ pair, const float* __restrict__ xyz,
    const float* __restrict__ g_pair, const float* __restrict__ b_pair,
    const float* __restrict__ We, const float* __restrict__ be,
    const float* __restrict__ g_edge, const float* __restrict__ b_edge,
    const float* __restrict__ Wa, const float* __restrict__ ba,
    const float* __restrict__ W0, const float* __restrict__ b0,
    const float* __restrict__ Wc1, const float* __restrict__ Wc2,
    const float* __restrict__ node, const int* __restrict__ cnt,
    const int* __restrict__ jlist, float* __restrict__ part)
{
  const int bid = blockIdx.x >> 2;     // (b,i)
  const int blk = blockIdx.x & (NBLK-1);
  const int b = bid >> 8;
  const int tid = threadIdx.x;
  const int r = tid >> 5, t = tid & 31;   // 8 groups of 32

  __shared__ h2 WeP[64*32];            // 8 KB
  __shared__ h2 WaP[16*32];            // 2 KB
  __shared__ float waD[32];
  __shared__ h2 W0P[48*16];            // 3 KB
  __shared__ h2 WcP[16*12];            // 768 B
  __shared__ float ndI[32];
  __shared__ float m0bS[16];
  __shared__ float beS[32], geS[32], beeS[32], baS[32];
  __shared__ int   jlS[64];            // this block's jlist chunk (chunk <= 64)
  __shared__ alignas(16) _Float16 pnH[16][128];   // 4 KB
  __shared__ alignas(16) _Float16 edH[16][32];    // 1 KB
  __shared__ alignas(16) _Float16 aH [16][32];    // 1 KB
  __shared__ alignas(16) _Float16 ndH[16][32];    // 1 KB
  __shared__ float cS[16*12];
  __shared__ float xjS[16][9];
  __shared__ float geoS[16][4];        // dx,dy,dz,dist per staged row
  __shared__ float redS[8][16];
  __shared__ float redO[8][9];

  // ---- pack weights to f16 pairs (one-time) ----
  for (int idx=tid; idx<64*32; idx+=256){
    int q=idx>>5, c=idx&31;
    WeP[idx] = mk2(We[(2*q)*32+c], We[(2*q+1)*32+c]);
  }
  for (int idx=tid; idx<16*32; idx+=256){
    int q=idx>>5, c=idx&31;
    WaP[idx] = mk2(Wa[(2*q)*32+c], Wa[(2*q+1)*32+c]);
  }
  if (tid<32){
    waD[tid] = Wa[32*32+tid];
    beS[tid] = be[tid]; geS[tid] = g_edge[tid];
    beeS[tid] = b_edge[tid]; baS[tid] = ba[tid];
    ndI[tid] = node[bid*32+tid];
  }
  for (int idx=tid; idx<48*16; idx+=256){
    int q=idx>>4, c=idx&15;
    W0P[idx] = mk2(W0[(2*q)*16+c], W0[(2*q+1)*16+c]);
  }
  for (int idx=tid; idx<16*12; idx+=256){
    int q=idx/12, c=idx-q*12;
    float lo = (c<3)? Wc1[(2*q)*3+c]   : Wc2[(2*q)*9+(c-3)];
    float hi = (c<3)? Wc1[(2*q+1)*3+c] : Wc2[(2*q+1)*9+(c-3)];
    WcP[idx] = mk2(lo, hi);
  }
  __syncthreads();

  const int n = cnt[bid];
  const int chunk = (n + NBLK - 1) >> 2;
  const int j0 = blk*chunk;
  const int nrows = min(j0+chunk, n) - j0;   // rows this block owns (may be <=0)

  // m0 base: b0 + node_i @ W0[32:64]  -> LDS (computed once by 16 lanes)
  if (tid<16){
    float acc = b0[tid];
    for (int k=0;k<32;k++) acc += ndI[k]*W0[(32+k)*16+tid];
    m0bS[tid] = acc;
  }
  if (tid<64) jlS[tid] = (tid < nrows) ? jlist[bid*256 + j0 + tid] : 0;
  __syncthreads();

  const float cax = xyz[(bid*3+1)*3+0];
  const float cay = xyz[(bid*3+1)*3+1];
  const float caz = xyz[(bid*3+1)*3+2];

  float stA = 0.f;   // t<16: state partial
  float ofA = 0.f;   // t<9 : offset partial

  for (int base=0; base<nrows; base+=16){
    bool vals[2];
    // ---- stage: pair-row LN -> pnH (f16), node_j -> ndH, xyz_j, geometry -> LDS ----
    {
      const float4 gp4 = *(const float4*)&g_pair[4*t];
      const float4 bp4 = *(const float4*)&b_pair[4*t];
      #pragma unroll
      for (int jc=0;jc<2;jc++){
        const int slot = base + r*2 + jc;
        vals[jc] = slot < nrows;
        const int jj = jlS[vals[jc] ? slot : 0];
        const int row = r*2+jc;
        const float* prow = &pair[((long)bid*256 + jj)*128];
        const float4 pv4 = *(const float4*)&prow[4*t];   // lane t owns k=4t..4t+3
        float s  = wred32(pv4.x+pv4.y+pv4.z+pv4.w);
        float s2 = wred32(pv4.x*pv4.x+pv4.y*pv4.y+pv4.z*pv4.z+pv4.w*pv4.w);
        float mu = s*(1.f/128.f);
        float var = s2*(1.f/128.f)-mu*mu;
        float rs = rsqrtf(var+EPSLN);
        h4 o;
        o[0]=(_Float16)((pv4.x-mu)*rs*gp4.x+bp4.x);
        o[1]=(_Float16)((pv4.y-mu)*rs*gp4.y+bp4.y);
        o[2]=(_Float16)((pv4.z-mu)*rs*gp4.z+bp4.z);
        o[3]=(_Float16)((pv4.w-mu)*rs*gp4.w+bp4.w);
        *(h4*)&pnH[row][4*t] = o;
        const int jb=(b<<8)+jj;
        ndH[row][t] = (_Float16)node[jb*32+t];
        if (t<9) xjS[row][t] = xyz[(size_t)jb*9 + t];
        if (t==0){
          float jx = xyz[(size_t)jb*9+3]-cax;
          float jy = xyz[(size_t)jb*9+4]-cay;
          float jz = xyz[(size_t)jb*9+5]-caz;
          geoS[row][0]=jx; geoS[row][1]=jy; geoS[row][2]=jz;
          geoS[row][3]=sqrtf(jx*jx+jy*jy+jz*jz);
        }
      }
    }
    // ---- edge GEMV (128->32) via fdot2, weights shared across 2 j ----
    float ea0[2], ea1[2];
    ea0[0]=ea0[1]=beS[t]; ea1[0]=ea1[1]=0.f;
    for (int q=0; q<64; q+=4){
      const h2 w0=WeP[(q+0)*32+t], w1=WeP[(q+1)*32+t], w2=WeP[(q+2)*32+t], w3=WeP[(q+3)*32+t];
      #pragma unroll
      for (int jc=0;jc<2;jc++){
        const h2* pr = (const h2*)&pnH[r*2+jc][0];
        ea0[jc]=FDOT2(w1, pr[q+1], FDOT2(w0, pr[q+0], ea0[jc]));
        ea1[jc]=FDOT2(w3, pr[q+3], FDOT2(w2, pr[q+2], ea1[jc]));
      }
    }
    // ---- edge LN (32) -> edH (f16) ----
    #pragma unroll
    for (int jc=0;jc<2;jc++){
      float acc=ea0[jc]+ea1[jc];
      float s=wred32(acc), s2=wred32(acc*acc);
      float mu=s*(1.f/32.f), var=s2*(1.f/32.f)-mu*mu;
      edH[r*2+jc][t] = (_Float16)((acc-mu)*rsqrtf(var+EPSLN)*geS[t]+beeS[t]);
    }
    // ---- a = relu([edge, dist] @ Wa + ba) -> aH (f16) ----
    float av[2];
    #pragma unroll
    for (int jc=0;jc<2;jc++) av[jc]=baS[t]+geoS[r*2+jc][3]*waD[t];
    for (int q=0; q<16; q+=4){
      const h2 w0=WaP[(q+0)*32+t], w1=WaP[(q+1)*32+t], w2=WaP[(q+2)*32+t], w3=WaP[(q+3)*32+t];
      #pragma unroll
      for (int jc=0;jc<2;jc++){
        const h2* ev = (const h2*)&edH[r*2+jc][0];
        av[jc]=FDOT2(w3, ev[q+3], FDOT2(w2, ev[q+2], FDOT2(w1, ev[q+1], FDOT2(w0, ev[q+0], av[jc]))));
      }
    }
    #pragma unroll
    for (int jc=0;jc<2;jc++) aH[r*2+jc][t]=(_Float16)fmaxf(av[jc],0.f);
    // ---- m0: a-part on lanes t<16, node_j-part on lanes t>=16, combine via shfl ----
    {
      const int half = t>>4, tc = t&15;
      const int qoff = half ? 32 : 0;      // W0 rows 64..95 for node_j part
      float m0v[2];
      m0v[0] = m0v[1] = half ? 0.f : m0bS[tc];
      for (int q=0;q<16;q+=4){
        const h2 w0=W0P[(qoff+q+0)*16+tc], w1=W0P[(qoff+q+1)*16+tc],
                 w2=W0P[(qoff+q+2)*16+tc], w3=W0P[(qoff+q+3)*16+tc];
        #pragma unroll
        for (int jc=0;jc<2;jc++){
          const _Float16* opb = half ? &ndH[r*2+jc][0] : &aH[r*2+jc][0];
          const h2* ov = (const h2*)opb;
          m0v[jc]=FDOT2(w3, ov[q+3], FDOT2(w2, ov[q+2], FDOT2(w1, ov[q+1], FDOT2(w0, ov[q+0], m0v[jc]))));
        }
      }
      #pragma unroll
      for (int jc=0;jc<2;jc++){
        float tot = m0v[jc] + __shfl_xor(m0v[jc], 16);
        if (t<16 && vals[jc]) stA += fmaxf(tot, 0.f);
      }
    }
    // ---- c1/c2 from a: lanes t<12 pairs 0..7, lanes 12..23 pairs 8..15 ----
    {
      const bool up = (t>=12 && t<24);
      const int tc12 = up ? t-12 : (t<12 ? t : 0);
      const int qb = up ? 8 : 0;
      float cv[2]={0.f,0.f};
      for (int q=0;q<8;q+=4){
        const h2 w0=WcP[(qb+q+0)*12+tc12], w1=WcP[(qb+q+1)*12+tc12],
                 w2=WcP[(qb+q+2)*12+tc12], w3=WcP[(qb+q+3)*12+tc12];
        #pragma unroll
        for (int jc=0;jc<2;jc++){
          const h2* av2 = (const h2*)&aH[r*2+jc][0];
          cv[jc]=FDOT2(w3, av2[qb+q+3], FDOT2(w2, av2[qb+q+2], FDOT2(w1, av2[qb+q+1], FDOT2(w0, av2[qb+q+0], cv[jc]))));
        }
      }
      #pragma unroll
      for (int jc=0;jc<2;jc++){
        const int src = (t<12) ? t+12 : (up ? t-12 : t);
        float other = __shfl(cv[jc], src, 32);
        if (t<12) cS[(r*2+jc)*12+t] = cv[jc]+other;
      }
    }
    // ---- offset accumulation (t<9), geometry from LDS ----
    if (t<9){
      const int o=t/3, x=t-o*3;
      #pragma unroll
      for (int jc=0;jc<2;jc++){
        if (!vals[jc]) continue;
        const int row=r*2+jc;
        const float dj = geoS[row][3];
        const float dh = geoS[row][x]/(dj+1e-8f);
        const float* cr = &cS[row*12];
        float val = cr[o]*dh;
        const float caxj = xjS[row][3+x];
        #pragma unroll
        for (int c=0;c<3;c++){
          val += cr[3+o*3+c]*(xjS[row][c*3+x]-caxj);
        }
        ofA += val;
      }
    }
  }

  if (t<16) redS[r][t]=stA;
  if (t<9)  redO[r][t]=ofA;
  __syncthreads();
  const int pbase = (bid*NBLK+blk)*28;
  if (tid<16){
    float s=0.f;
    for (int r2=0;r2<8;r2++) s+=redS[r2][tid];
    part[pbase + tid] = s;
  }
  if (tid>=32 && tid<41){
    float s=0.f;
    for (int r2=0;r2<8;r2++) s+=redO[r2][tid-32];
    part[pbase + 16 + (tid-32)] = s;
  }
}

// ---------------- Kernel F: combine partials, scale by deg, form xyz_new ----------------
// grid = B*L (512), block = 64
__global__ __launch_bounds__(64) void k_fin(
    const float* __restrict__ xyz, const int* __restrict__ cnt,
    const float* __restrict__ part, float* __restrict__ out)
{
  const int bid = blockIdx.x;
  const int t = threadIdx.x;
  __shared__ float offF[9];
  const int n = cnt[bid];
  const float invd = 1.f/fmaxf((float)n,1.f);
  if (t<16){
    float s=0.f;
    #pragma unroll
    for (int k2=0;k2<NBLK;k2++) s += part[(bid*NBLK+k2)*28 + t];
    out[4608 + bid*16 + t] = s*invd;           // state
  } else if (t<25){
    float s=0.f;
    #pragma unroll
    for (int k2=0;k2<NBLK;k2++) s += part[(bid*NBLK+k2)*28 + t];
    offF[t-16] = s*invd;
  }
  __syncthreads();
  if (t<9){
    const int o=t/3, x=t-o*3;
    const float cac = xyz[(bid*3+1)*3+x];
    const float CA = cac + offF[3+x];          // offset[:,:,1]
    const float v = (o==1)? CA : (CA + offF[o*3+x]);
    out[bid*9 + t] = v;                        // xyz_new
  }
}

extern "C" void kernel_launch(void* const* d_in, const int* in_sizes, int n_in,
                              void* d_out, int out_size, void* d_ws, size_t ws_size,
                              hipStream_t stream)
{
  const float* msa     = (const float*)d_in[0];
  const float* pair    = (const float*)d_in[1];
  const float* xyz     = (const float*)d_in[2];
  const float* seq1hot = (const float*)d_in[3];
  const float* g_msa   = (const float*)d_in[4];
  const float* b_msa   = (const float*)d_in[5];
  const float* g_pair  = (const float*)d_in[6];
  const float* b_pair  = (const float*)d_in[7];
  const float* Wq      = (const float*)d_in[8];
  const float* bq      = (const float*)d_in[9];
  const float* Wk      = (const float*)d_in[10];
  const float* bk      = (const float*)d_in[11];
  const float* Wx      = (const float*)d_in[12];
  const float* bx      = (const float*)d_in[13];
  const float* g_node  = (const float*)d_in[14];
  const float* b_node  = (const float*)d_in[15];
  const float* We      = (const float*)d_in[16];
  const float* be      = (const float*)d_in[17];
  const float* g_edge  = (const float*)d_in[18];
  const float* b_edge  = (const float*)d_in[19];
  const float* Wa      = (const float*)d_in[20];
  const float* ba      = (const float*)d_in[21];
  const float* W0      = (const float*)d_in[22];
  const float* b0      = (const float*)d_in[23];
  const float* Wc1     = (const float*)d_in[24];
  const float* Wc2     = (const float*)d_in[25];
  const int*   idx     = (const int*)d_in[26];
  const int*   topk    = (const int*)d_in[27];
  float* out = (float*)d_out;

  float* node = (float*)d_ws;                     // 16384 f32
  int* cnt    = (int*)((char*)d_ws + 16384*4);    // 512 i32
  int* jlist  = cnt + 512;                        // 131072 i32
  float* part = (float*)(jlist + 131072);         // 512*NBLK*28 f32 (~229 KB)

  k_prep<<<512, 256, 0, stream>>>(msa, seq1hot, xyz, idx, topk, g_msa, b_msa,
                                  Wq, bq, Wk, bk, Wx, bx, g_node, b_node,
                                  node, cnt, jlist);
  k_main<<<512*NBLK, 256, 0, stream>>>(pair, xyz, g_pair, b_pair, We, be, g_edge, b_edge,
                                       Wa, ba, W0, b0, Wc1, Wc2, node, cnt, jlist, part);
  k_fin<<<512, 64, 0, stream>>>(xyz, cnt, part, out);
}

// Round 7
// 52.190 us; speedup vs baseline: 1.1986x; 1.1986x over previous
//
#include <hip/hip_runtime.h>

#define EPSLN 1e-5f
#define KMINC 9
#define SLI   10         // slices per (b,i), 8 rows each -> covers n <= 80 (top_k=64 + <=16 seq-neighbors)

typedef _Float16 h2 __attribute__((ext_vector_type(2)));
typedef _Float16 h4 __attribute__((ext_vector_type(4)));

#if defined(__has_builtin)
#if __has_builtin(__builtin_amdgcn_fdot2)
#define FDOT2(a,b,c) __builtin_amdgcn_fdot2((a),(b),(c),false)
#endif
#endif
#ifndef FDOT2
#define FDOT2(a,b,c) ((c) + (float)(a)[0]*(float)(b)[0] + (float)(a)[1]*(float)(b)[1])
#endif

__device__ __forceinline__ h2 mk2(float a, float b){
  h2 v; v[0]=(_Float16)a; v[1]=(_Float16)b; return v;
}
__device__ __forceinline__ unsigned h2bits(h2 v){
  union { h2 h; unsigned u; } c; c.h = v; return c.u;
}

__device__ __forceinline__ float wred64(float v){
  #pragma unroll
  for (int m=1;m<64;m<<=1) v += __shfl_xor(v,m,64);
  return v;
}
__device__ __forceinline__ float wred32(float v){
  #pragma unroll
  for (int m=1;m<32;m<<=1) v += __shfl_xor(v,m,64);
  return v;
}

// ws word-offsets
#define WS_NODE   0
#define WS_CNT    16384
#define WS_JLIST  16896       // 512*96 ints
#define WS_M0B    66048       // 512*16 f32
#define WS_PART   74240       // 512*SLI*28 f32 = 143360
#define WS_PACKW  217600      // 2048(We)+512(Wa)+768(W0)+192(Wc) u32 + 32 f32(waD)

// ---------------- Kernel P: msa-LN/attention/node + m0b + top-k mask + weight packing ----------------
// grid = B*L (512), block = 256
__global__ __launch_bounds__(256) void k_prep(
    const float* __restrict__ msa, const float* __restrict__ seq1hot,
    const float* __restrict__ xyz, const int* __restrict__ idxp,
    const int* __restrict__ topk,
    const float* __restrict__ g_msa, const float* __restrict__ b_msa,
    const float* __restrict__ Wq, const float* __restrict__ bq,
    const float* __restrict__ Wk, const float* __restrict__ bk,
    const float* __restrict__ Wx, const float* __restrict__ bx,
    const float* __restrict__ g_node, const float* __restrict__ b_node,
    const float* __restrict__ We, const float* __restrict__ Wa,
    const float* __restrict__ W0, const float* __restrict__ b0,
    const float* __restrict__ Wc1, const float* __restrict__ Wc2,
    float* __restrict__ node, int* __restrict__ cnt, int* __restrict__ jlist,
    float* __restrict__ m0bG, unsigned* __restrict__ packW)
{
  const int bid = blockIdx.x;          // b*256 + l  (l == i)
  const int b = bid >> 8;
  const int tid = threadIdx.x;
  const int w = tid >> 6, lane = tid & 63;

  __shared__ float mn[32][64];
  __shared__ float qS[64];
  __shared__ float scS[32];
  __shared__ float redS[4][64];
  __shared__ float ssumS[4];
  __shared__ float nodeS[32];
  __shared__ float Dv[256];
  __shared__ int   wsum[4];

  // ---- block 0 additionally packs weights to f16 in ws (for k_main) ----
  if (bid==0){
    for (int i=tid;i<2048;i+=256){ int q=i>>5,c=i&31; packW[i]        = h2bits(mk2(We[(2*q)*32+c], We[(2*q+1)*32+c])); }
    for (int i=tid;i<512; i+=256){ int q=i>>5,c=i&31; packW[2048+i]   = h2bits(mk2(Wa[(2*q)*32+c], Wa[(2*q+1)*32+c])); }
    for (int i=tid;i<768; i+=256){ int q=i>>4,c=i&15; packW[2560+i]   = h2bits(mk2(W0[(2*q)*16+c], W0[(2*q+1)*16+c])); }
    if (tid<192){
      int q=tid/12, c=tid-q*12;
      float lo = (c<3)? Wc1[(2*q)*3+c]   : Wc2[(2*q)*9+(c-3)];
      float hi = (c<3)? Wc1[(2*q+1)*3+c] : Wc2[(2*q+1)*9+(c-3)];
      packW[3328+tid] = h2bits(mk2(lo,hi));
    }
    if (tid<32) ((float*)packW)[3520+tid] = Wa[32*32+tid];
  }

  const float gm = g_msa[lane], bm = b_msa[lane];
  for (int nn=w; nn<32; nn+=4){
    float x = msa[(size_t)(((b*32+nn)<<8)+(bid&255))*64 + lane];
    float s = wred64(x), s2 = wred64(x*x);
    float mu = s*(1.f/64.f);
    float var = s2*(1.f/64.f) - mu*mu;
    mn[nn][lane] = (x-mu)*rsqrtf(var+EPSLN)*gm + bm;
  }
  __syncthreads();
  if (w==0){
    float q = bq[lane];
    for (int d=0; d<64; d++) q += mn[0][d]*Wq[d*64+lane];
    qS[lane] = q*0.125f;               // 1/sqrt(64)
  }
  __syncthreads();
  {
    float partial = 0.f;
    for (int e=w*16; e<w*16+16; e++) partial += Wk[lane*64+e]*qS[e];
    redS[w][lane] = partial;
  }
  __syncthreads();
  const float qk = redS[0][lane]+redS[1][lane]+redS[2][lane]+redS[3][lane];
  const float qb = wred64(qS[lane]*bk[lane]);
  for (int nn=w*8; nn<w*8+8; nn++){
    float p = wred64(mn[nn][lane]*qk);
    if (lane==0) scS[nn] = p + qb;
  }
  __syncthreads();
  float mx = -1e30f;
  for (int nn=0; nn<32; nn++) mx = fmaxf(mx, scS[nn]);
  float ps=0.f, pm=0.f;
  for (int nn=w*8; nn<w*8+8; nn++){
    float e = expf(scS[nn]-mx);
    ps += e; pm += e*mn[nn][lane];
  }
  redS[w][lane] = pm;
  if (lane==0) ssumS[w] = ps;
  __syncthreads();
  if (w==0){
    float ssum = ssumS[0]+ssumS[1]+ssumS[2]+ssumS[3];
    qS[lane] = (redS[0][lane]+redS[1][lane]+redS[2][lane]+redS[3][lane]) / ssum;
  }
  __syncthreads();
  if (tid<32){
    float acc = bx[tid];
    for (int k=0;k<64;k++) acc += qS[k]*Wx[k*32+tid];
    const float* s1 = &seq1hot[bid*21];
    for (int k=0;k<21;k++) acc += s1[k]*Wx[(64+k)*32+tid];
    float s = wred32(acc), s2 = wred32(acc*acc);
    float mu = s*(1.f/32.f), var = s2*(1.f/32.f)-mu*mu;
    float v = (acc-mu)*rsqrtf(var+EPSLN)*g_node[tid] + b_node[tid];
    node[bid*32+tid] = v;
    nodeS[tid] = v;
  }
  __syncthreads();
  // m0 base per (b,i): b0 + node_i @ W0[32:64]
  if (tid<16){
    float acc = b0[tid];
    for (int k=0;k<32;k++) acc += nodeS[k]*W0[(32+k)*16+tid];
    m0bG[bid*16+tid] = acc;
  }

  // --- Phase 2: distances, exact stable top-k rank, compaction (thread = j) ---
  const int i = bid & 255;
  const int j = tid;
  const float cax = xyz[(bid*3+1)*3+0];
  const float cay = xyz[(bid*3+1)*3+1];
  const float caz = xyz[(bid*3+1)*3+2];
  const int jb = (b<<8)+j;
  float dx = xyz[(jb*3+1)*3+0]-cax;
  float dy = xyz[(jb*3+1)*3+1]-cay;
  float dz = xyz[(jb*3+1)*3+2]-caz;
  float D = sqrtf(dx*dx+dy*dy+dz*dz) + (i==j ? 999.9f : 0.f);
  __syncthreads();
  Dv[j] = D;
  __syncthreads();
  int rank = 0;
  for (int j2=0;j2<256;j2++){
    float v = Dv[j2];
    rank += (v < D || (v == D && j2 < j)) ? 1 : 0;
  }
  int K = topk[0];
  if (K<=0 || K>256){
    float f = ((const float*)topk)[0];
    K = (f>=1.f && f<=256.f) ? (int)f : 64;
  }
  const int sep = abs(idxp[jb] - idxp[bid]);
  const bool m = (rank < K) || (i!=j && sep < KMINC);
  unsigned long long bal = __ballot(m);
  const int l6 = j & 63, wv = j >> 6;
  const int pre = __popcll(bal & ((1ull<<l6)-1ull));
  if (l6==0) wsum[wv] = __popcll(bal);
  __syncthreads();
  int off = 0;
  for (int w2=0;w2<wv;w2++) off += wsum[w2];
  if (m) jlist[bid*96 + off + pre] = j;
  if (j==0) cnt[bid] = wsum[0]+wsum[1]+wsum[2]+wsum[3];
}

// ---------------- Kernel C: wave-per-slice gathered pipeline ----------------
// grid = 512*SLI/4 (1280), block = 256 = 4 independent waves.
// Wave handles ONE 8-row slice of one (b,i): no loop, no block-level coupling,
// one dependency-chain traversal per wave. All 5120 waves co-resident (LDS ~30KB -> 5 blk/CU).
__global__ __launch_bounds__(256) void k_main(
    const float* __restrict__ pair, const float* __restrict__ xyz,
    const float* __restrict__ g_pair, const float* __restrict__ b_pair,
    const float* __restrict__ be, const float* __restrict__ g_edge,
    const float* __restrict__ b_edge, const float* __restrict__ ba,
    const float* __restrict__ node, const int* __restrict__ cnt,
    const int* __restrict__ jlist, const float* __restrict__ m0bG,
    const unsigned* __restrict__ packW, float* __restrict__ part)
{
  const int tid = threadIdx.x;
  const int w  = tid >> 6;          // wave 0..3
  const int wl = tid & 63;          // lane in wave
  const int r  = (tid >> 5) & 1;    // group in wave
  const int t  = tid & 31;          // lane in group

  __shared__ h2 WeP[64*32];                         // 8 KB
  __shared__ h2 WaP[16*32];                         // 2 KB
  __shared__ h2 W0P[48*16];                         // 3 KB
  __shared__ h2 WcP[16*12];                         // 768 B
  __shared__ float waD[32];
  __shared__ float beS[32], geS[32], beeS[32], baS[32];
  __shared__ alignas(16) _Float16 pnH[32][128];     // 8 KB
  __shared__ alignas(8)  _Float16 edH[32][32];      // 2 KB
  __shared__ alignas(8)  _Float16 aH [32][32];      // 2 KB
  __shared__ alignas(8)  _Float16 ndH[32][32];      // 2 KB
  __shared__ float cS[32*12];
  __shared__ float xjS[32][9];
  __shared__ float geoS[32][4];

  // ---- copy prepacked weights from ws (coalesced u32) ----
  for (int i2=tid;i2<2048;i2+=256) ((unsigned*)WeP)[i2] = packW[i2];
  for (int i2=tid;i2<512; i2+=256) ((unsigned*)WaP)[i2] = packW[2048+i2];
  for (int i2=tid;i2<768; i2+=256) ((unsigned*)W0P)[i2] = packW[2560+i2];
  if (tid<192) ((unsigned*)WcP)[tid] = packW[3328+tid];
  if (tid<32){
    waD[tid] = ((const float*)packW)[3520+tid];
    beS[tid]=be[tid]; geS[tid]=g_edge[tid]; beeS[tid]=b_edge[tid]; baS[tid]=ba[tid];
  }
  __syncthreads();        // the ONLY block-wide barrier

  const int s    = blockIdx.x*4 + w;   // slice id, < 512*SLI
  const int item = s / SLI;            // (b,i)
  const int sl   = s - item*SLI;
  const int b    = item >> 8;
  const int n    = cnt[item];
  const int row0 = sl*8;               // this wave's rows: [row0, row0+8)
  const int wrow = w*8;                // LDS row base

  float stA = 0.f;   // t<16 of each group: state partial
  float ofA = 0.f;   // t<9  of each group: offset partial

  if (row0 < n){
    const float cax = xyz[(item*3+1)*3+0];
    const float cay = xyz[(item*3+1)*3+1];
    const float caz = xyz[(item*3+1)*3+2];
    bool vals[4];
    // ---- stage 4 rows per group: pair LN -> pnH f16, node_j, xyz_j, geometry ----
    {
      const float4 gp4 = *(const float4*)&g_pair[4*t];
      const float4 bp4 = *(const float4*)&b_pair[4*t];
      #pragma unroll
      for (int jc=0;jc<4;jc++){
        const int slot = row0 + r*4 + jc;
        vals[jc] = slot < n;
        const int jj = vals[jc] ? jlist[item*96 + slot] : 0;
        const int row = wrow + r*4 + jc;
        const float* prow = &pair[((long)item*256 + jj)*128];
        const float4 pv4 = *(const float4*)&prow[4*t];   // lane t owns k=4t..4t+3
        float sm  = wred32(pv4.x+pv4.y+pv4.z+pv4.w);
        float sm2 = wred32(pv4.x*pv4.x+pv4.y*pv4.y+pv4.z*pv4.z+pv4.w*pv4.w);
        float mu = sm*(1.f/128.f);
        float var = sm2*(1.f/128.f)-mu*mu;
        float rs = rsqrtf(var+EPSLN);
        h4 o;
        o[0]=(_Float16)((pv4.x-mu)*rs*gp4.x+bp4.x);
        o[1]=(_Float16)((pv4.y-mu)*rs*gp4.y+bp4.y);
        o[2]=(_Float16)((pv4.z-mu)*rs*gp4.z+bp4.z);
        o[3]=(_Float16)((pv4.w-mu)*rs*gp4.w+bp4.w);
        *(h4*)&pnH[row][4*t] = o;
        const int jb=(b<<8)+jj;
        ndH[row][t] = (_Float16)node[jb*32+t];
        if (t<9) xjS[row][t] = xyz[(size_t)jb*9 + t];
        if (t==0){
          float jx = xyz[(size_t)jb*9+3]-cax;
          float jy = xyz[(size_t)jb*9+4]-cay;
          float jz = xyz[(size_t)jb*9+5]-caz;
          geoS[row][0]=jx; geoS[row][1]=jy; geoS[row][2]=jz;
          geoS[row][3]=sqrtf(jx*jx+jy*jy+jz*jz);
        }
      }
    }
    // ---- edge GEMV (128->32), 4-row weight reuse ----
    float ea0[4], ea1[4];
    #pragma unroll
    for (int jc=0;jc<4;jc++){ ea0[jc]=beS[t]; ea1[jc]=0.f; }
    for (int q=0; q<64; q+=4){
      const h2 w0=WeP[(q+0)*32+t], w1=WeP[(q+1)*32+t], w2=WeP[(q+2)*32+t], w3=WeP[(q+3)*32+t];
      #pragma unroll
      for (int jc=0;jc<4;jc++){
        const h2* pr = (const h2*)&pnH[wrow + r*4 + jc][0];
        ea0[jc]=FDOT2(w1, pr[q+1], FDOT2(w0, pr[q+0], ea0[jc]));
        ea1[jc]=FDOT2(w3, pr[q+3], FDOT2(w2, pr[q+2], ea1[jc]));
      }
    }
    // ---- edge LN -> edH f16 ----
    #pragma unroll
    for (int jc=0;jc<4;jc++){
      float acc=ea0[jc]+ea1[jc];
      float sm=wred32(acc), sm2=wred32(acc*acc);
      float mu=sm*(1.f/32.f), var=sm2*(1.f/32.f)-mu*mu;
      edH[wrow + r*4 + jc][t] = (_Float16)((acc-mu)*rsqrtf(var+EPSLN)*geS[t]+beeS[t]);
    }
    // ---- a = relu([edge, dist] @ Wa + ba) -> aH f16 ----
    float av[4];
    #pragma unroll
    for (int jc=0;jc<4;jc++) av[jc]=baS[t]+geoS[wrow + r*4 + jc][3]*waD[t];
    for (int q=0; q<16; q+=4){
      const h2 w0=WaP[(q+0)*32+t], w1=WaP[(q+1)*32+t], w2=WaP[(q+2)*32+t], w3=WaP[(q+3)*32+t];
      #pragma unroll
      for (int jc=0;jc<4;jc++){
        const h2* ev = (const h2*)&edH[wrow + r*4 + jc][0];
        av[jc]=FDOT2(w3, ev[q+3], FDOT2(w2, ev[q+2], FDOT2(w1, ev[q+1], FDOT2(w0, ev[q+0], av[jc]))));
      }
    }
    #pragma unroll
    for (int jc=0;jc<4;jc++) aH[wrow + r*4 + jc][t]=(_Float16)fmaxf(av[jc],0.f);
    // ---- m0: a-part lanes t<16, node_j-part lanes t>=16, combine via shfl_xor(16) ----
    {
      const int half = t>>4, tc = t&15;
      const int qoff = half ? 32 : 0;      // W0 rows 64..95 for node_j part
      const float m0b = half ? 0.f : m0bG[item*16+tc];
      float m0v[4];
      #pragma unroll
      for (int jc=0;jc<4;jc++) m0v[jc]=m0b;
      for (int q=0;q<16;q+=4){
        const h2 w0=W0P[(qoff+q+0)*16+tc], w1=W0P[(qoff+q+1)*16+tc],
                 w2=W0P[(qoff+q+2)*16+tc], w3=W0P[(qoff+q+3)*16+tc];
        #pragma unroll
        for (int jc=0;jc<4;jc++){
          const _Float16* opb = half ? &ndH[wrow + r*4 + jc][0] : &aH[wrow + r*4 + jc][0];
          const h2* ov = (const h2*)opb;
          m0v[jc]=FDOT2(w3, ov[q+3], FDOT2(w2, ov[q+2], FDOT2(w1, ov[q+1], FDOT2(w0, ov[q+0], m0v[jc]))));
        }
      }
      #pragma unroll
      for (int jc=0;jc<4;jc++){
        float tot = m0v[jc] + __shfl_xor(m0v[jc], 16);
        if (t<16 && vals[jc]) stA += fmaxf(tot, 0.f);
      }
    }
    // ---- c1/c2 from a: lanes t<12 pairs 0..7, lanes 12..23 pairs 8..15 ----
    {
      const bool up = (t>=12 && t<24);
      const int tc12 = up ? t-12 : (t<12 ? t : 0);
      const int qb = up ? 8 : 0;
      float cv[4]={0.f,0.f,0.f,0.f};
      for (int q=0;q<8;q+=4){
        const h2 w0=WcP[(qb+q+0)*12+tc12], w1=WcP[(qb+q+1)*12+tc12],
                 w2=WcP[(qb+q+2)*12+tc12], w3=WcP[(qb+q+3)*12+tc12];
        #pragma unroll
        for (int jc=0;jc<4;jc++){
          const h2* av2 = (const h2*)&aH[wrow + r*4 + jc][0];
          cv[jc]=FDOT2(w3, av2[qb+q+3], FDOT2(w2, av2[qb+q+2], FDOT2(w1, av2[qb+q+1], FDOT2(w0, av2[qb+q+0], cv[jc]))));
        }
      }
      #pragma unroll
      for (int jc=0;jc<4;jc++){
        const int src = (t<12) ? t+12 : (up ? t-12 : t);
        float other = __shfl(cv[jc], src, 32);
        if (t<12) cS[(wrow + r*4 + jc)*12+t] = cv[jc]+other;
      }
    }
    // ---- offset accumulation (t<9) ----
    if (t<9){
      const int o=t/3, x=t-o*3;
      #pragma unroll
      for (int jc=0;jc<4;jc++){
        if (!vals[jc]) continue;
        const int row = wrow + r*4 + jc;
        const float dj = geoS[row][3];
        const float dh = geoS[row][x]/(dj+1e-8f);
        const float* cr = &cS[row*12];
        float val = cr[o]*dh;
        const float caxj = xjS[row][3+x];
        #pragma unroll
        for (int c=0;c<3;c++){
          val += cr[3+o*3+c]*(xjS[row][c*3+x]-caxj);
        }
        ofA += val;
      }
    }
  }

  // ---- combine the wave's two groups and write this slice's partial (zeros if empty) ----
  stA += __shfl_xor(stA, 32);
  ofA += __shfl_xor(ofA, 32);
  if (wl < 16) part[s*28 + wl] = stA;
  if (wl < 9)  part[s*28 + 16 + wl] = ofA;
}

// ---------------- Kernel F: combine partials, scale by deg, form xyz_new ----------------
// grid = B*L (512), block = 64
__global__ __launch_bounds__(64) void k_fin(
    const float* __restrict__ xyz, const int* __restrict__ cnt,
    const float* __restrict__ part, float* __restrict__ out)
{
  const int bid = blockIdx.x;
  const int t = threadIdx.x;
  __shared__ float offF[9];
  const int n = cnt[bid];
  const float invd = 1.f/fmaxf((float)n,1.f);
  if (t<16){
    float s=0.f;
    #pragma unroll
    for (int k2=0;k2<SLI;k2++) s += part[(bid*SLI+k2)*28 + t];
    out[4608 + bid*16 + t] = s*invd;           // state
  } else if (t<25){
    float s=0.f;
    #pragma unroll
    for (int k2=0;k2<SLI;k2++) s += part[(bid*SLI+k2)*28 + t];
    offF[t-16] = s*invd;
  }
  __syncthreads();
  if (t<9){
    const int o=t/3, x=t-o*3;
    const float cac = xyz[(bid*3+1)*3+x];
    const float CA = cac + offF[3+x];          // offset[:,:,1]
    const float v = (o==1)? CA : (CA + offF[o*3+x]);
    out[bid*9 + t] = v;                        // xyz_new
  }
}

extern "C" void kernel_launch(void* const* d_in, const int* in_sizes, int n_in,
                              void* d_out, int out_size, void* d_ws, size_t ws_size,
                              hipStream_t stream)
{
  const float* msa     = (const float*)d_in[0];
  const float* pair    = (const float*)d_in[1];
  const float* xyz     = (const float*)d_in[2];
  const float* seq1hot = (const float*)d_in[3];
  const float* g_msa   = (const float*)d_in[4];
  const float* b_msa   = (const float*)d_in[5];
  const float* g_pair  = (const float*)d_in[6];
  const float* b_pair  = (const float*)d_in[7];
  const float* Wq      = (const float*)d_in[8];
  const float* bq      = (const float*)d_in[9];
  const float* Wk      = (const float*)d_in[10];
  const float* bk      = (const float*)d_in[11];
  const float* Wx      = (const float*)d_in[12];
  const float* bx      = (const float*)d_in[13];
  const float* g_node  = (const float*)d_in[14];
  const float* b_node  = (const float*)d_in[15];
  const float* We      = (const float*)d_in[16];
  const float* be      = (const float*)d_in[17];
  const float* g_edge  = (const float*)d_in[18];
  const float* b_edge  = (const float*)d_in[19];
  const float* Wa      = (const float*)d_in[20];
  const float* ba      = (const float*)d_in[21];
  const float* W0      = (const float*)d_in[22];
  const float* b0      = (const float*)d_in[23];
  const float* Wc1     = (const float*)d_in[24];
  const float* Wc2     = (const float*)d_in[25];
  const int*   idx     = (const int*)d_in[26];
  const int*   topk    = (const int*)d_in[27];
  float* out = (float*)d_out;

  float* wsf = (float*)d_ws;
  float*    node  = wsf + WS_NODE;
  int*      cnt   = (int*)(wsf + WS_CNT);
  int*      jlist = (int*)(wsf + WS_JLIST);
  float*    m0bG  = wsf + WS_M0B;
  float*    partb = wsf + WS_PART;
  unsigned* packW = (unsigned*)(wsf + WS_PACKW);

  k_prep<<<512, 256, 0, stream>>>(msa, seq1hot, xyz, idx, topk, g_msa, b_msa,
                                  Wq, bq, Wk, bk, Wx, bx, g_node, b_node,
                                  We, Wa, W0, b0, Wc1, Wc2,
                                  node, cnt, jlist, m0bG, packW);
  k_main<<<512*SLI/4, 256, 0, stream>>>(pair, xyz, g_pair, b_pair, be, g_edge,
                                        b_edge, ba, node, cnt, jlist, m0bG,
                                        packW, partb);
  k_fin<<<512, 64, 0, stream>>>(xyz, cnt, partb, out);
}

// Round 8
// 47.291 us; speedup vs baseline: 1.3227x; 1.1036x over previous
//
#include <hip/hip_runtime.h>

#define EPSLN 1e-5f
#define KMINC 9
#define SLI   10         // slices per (b,i), 8 rows each -> covers n <= 80

typedef _Float16 h2 __attribute__((ext_vector_type(2)));
typedef _Float16 h4 __attribute__((ext_vector_type(4)));

#if defined(__has_builtin)
#if __has_builtin(__builtin_amdgcn_fdot2)
#define FDOT2(a,b,c) __builtin_amdgcn_fdot2((a),(b),(c),false)
#endif
#endif
#ifndef FDOT2
#define FDOT2(a,b,c) ((c) + (float)(a)[0]*(float)(b)[0] + (float)(a)[1]*(float)(b)[1])
#endif

__device__ __forceinline__ h2 mk2(float a, float b){
  h2 v; v[0]=(_Float16)a; v[1]=(_Float16)b; return v;
}
__device__ __forceinline__ unsigned h2bits(h2 v){
  union { h2 h; unsigned u; } c; c.h = v; return c.u;
}
__device__ __forceinline__ h2 asH2(unsigned u){
  union { unsigned u; h2 h; } c; c.u = u; return c.h;
}

__device__ __forceinline__ float wred64(float v){
  #pragma unroll
  for (int m=1;m<64;m<<=1) v += __shfl_xor(v,m,64);
  return v;
}
__device__ __forceinline__ float wred32(float v){
  #pragma unroll
  for (int m=1;m<32;m<<=1) v += __shfl_xor(v,m,64);
  return v;
}

// ws word-offsets
#define WS_NODE   0
#define WS_CNT    16384
#define WS_JLIST  16896       // 512*96 ints
#define WS_M0B    66048       // 512*16 f32
#define WS_PART   74240       // 512*SLI*28 f32 = 143360
#define WS_PACKW  217600      // q-blocked packed weights (3552 u32)

// ---------------- Kernel P: msa-LN/attention/node + m0b + top-k mask + weight packing ----------------
// grid = B*L (512), block = 512 (8 waves)
__global__ __launch_bounds__(512) void k_prep(
    const float* __restrict__ msa, const float* __restrict__ seq1hot,
    const float* __restrict__ xyz, const int* __restrict__ idxp,
    const int* __restrict__ topk,
    const float* __restrict__ g_msa, const float* __restrict__ b_msa,
    const float* __restrict__ Wq, const float* __restrict__ bq,
    const float* __restrict__ Wk, const float* __restrict__ bk,
    const float* __restrict__ Wx, const float* __restrict__ bx,
    const float* __restrict__ g_node, const float* __restrict__ b_node,
    const float* __restrict__ We, const float* __restrict__ Wa,
    const float* __restrict__ W0, const float* __restrict__ b0,
    const float* __restrict__ Wc1, const float* __restrict__ Wc2,
    float* __restrict__ node, int* __restrict__ cnt, int* __restrict__ jlist,
    float* __restrict__ m0bG, unsigned* __restrict__ packW)
{
  const int bid = blockIdx.x;          // b*256 + l  (l == i)
  const int b = bid >> 8;
  const int tid = threadIdx.x;
  const int w = tid >> 6, lane = tid & 63;   // 8 waves

  __shared__ float mn[32][64];
  __shared__ float qS[64];
  __shared__ float scS[32];
  __shared__ float redS[8][64];
  __shared__ float ssumS[8];
  __shared__ float nodeS[32];
  __shared__ alignas(16) float Dv[256];
  __shared__ int   wsum[4];

  // ---- block 0 packs weights q-blocked f16 into ws (for k_main) ----
  // We_blk:  [qb<16][t<32][i<4]  word = h2(We rows (8qb+2i, 8qb+2i+1), col t)
  // Wa_blk:  [qb<4 ][t<32][i<4]
  // W0_blk:  [qb<12][tc<16][i<4]
  // Wc_blk:  [qb<4 ][tc<12][i<4]
  if (bid==0){
    for (int i=tid;i<2048;i+=512){
      int qb=i>>7, r7=i&127, t=r7>>2, i2=r7&3, q=4*qb+i2;
      packW[i] = h2bits(mk2(We[(2*q)*32+t], We[(2*q+1)*32+t]));
    }
    for (int i=tid;i<512; i+=512){
      int qb=i>>7, r7=i&127, t=r7>>2, i2=r7&3, q=4*qb+i2;
      packW[2048+i] = h2bits(mk2(Wa[(2*q)*32+t], Wa[(2*q+1)*32+t]));
    }
    for (int i=tid;i<768; i+=512){
      int qb=i>>6, r6=i&63, tc=r6>>2, i2=r6&3, q=4*qb+i2;
      packW[2560+i] = h2bits(mk2(W0[(2*q)*16+tc], W0[(2*q+1)*16+tc]));
    }
    if (tid<192){
      int qb=tid/48, r48=tid%48, tc=r48>>2, i2=r48&3, q=4*qb+i2;
      float lo = (tc<3)? Wc1[(2*q)*3+tc]   : Wc2[(2*q)*9+(tc-3)];
      float hi = (tc<3)? Wc1[(2*q+1)*3+tc] : Wc2[(2*q+1)*9+(tc-3)];
      packW[3328+tid] = h2bits(mk2(lo,hi));
    }
    if (tid<32) ((float*)packW)[3520+tid] = Wa[32*32+tid];
  }

  // ---- msa LN: wave w rows w, w+8, w+16, w+24 ----
  const float gm = g_msa[lane], bm = b_msa[lane];
  for (int nn=w; nn<32; nn+=8){
    float x = msa[(size_t)(((b*32+nn)<<8)+(bid&255))*64 + lane];
    float s = wred64(x), s2 = wred64(x*x);
    float mu = s*(1.f/64.f);
    float var = s2*(1.f/64.f) - mu*mu;
    mn[nn][lane] = (x-mu)*rsqrtf(var+EPSLN)*gm + bm;
  }
  __syncthreads();
  // ---- q[e=lane]: partial over d-range per wave ----
  {
    float p = (w==0)? bq[lane] : 0.f;
    for (int d=w*8; d<w*8+8; d++) p += mn[0][d]*Wq[d*64+lane];
    redS[w][lane] = p;
  }
  __syncthreads();
  if (w==0){
    float q = 0.f;
    #pragma unroll
    for (int k=0;k<8;k++) q += redS[k][lane];
    qS[lane] = q*0.125f;               // 1/sqrt(64)
  }
  __syncthreads();
  // ---- qk[d=lane]: partial over e-range per wave ----
  {
    float p = 0.f;
    for (int e=w*8; e<w*8+8; e++) p += Wk[lane*64+e]*qS[e];
    redS[w][lane] = p;
  }
  __syncthreads();
  float qk = 0.f;
  #pragma unroll
  for (int k=0;k<8;k++) qk += redS[k][lane];
  const float qb_ = wred64(qS[lane]*bk[lane]);
  // ---- scores: wave w rows w*4..w*4+3 ----
  for (int nn=w*4; nn<w*4+4; nn++){
    float p = wred64(mn[nn][lane]*qk);
    if (lane==0) scS[nn] = p + qb_;
  }
  __syncthreads();
  // ---- softmax + weighted msa ----
  float mx = -1e30f;
  for (int nn=0; nn<32; nn++) mx = fmaxf(mx, scS[nn]);
  float ps=0.f, pm=0.f;
  for (int nn=w*4; nn<w*4+4; nn++){
    float e = expf(scS[nn]-mx);
    ps += e; pm += e*mn[nn][lane];
  }
  redS[w][lane] = pm;
  if (lane==0) ssumS[w] = ps;
  __syncthreads();
  if (w==0){
    float ssum = 0.f, acc = 0.f;
    #pragma unroll
    for (int k=0;k<8;k++){ ssum += ssumS[k]; acc += redS[k][lane]; }
    qS[lane] = acc / ssum;
  }
  __syncthreads();
  if (tid<32){
    float acc = bx[tid];
    for (int k=0;k<64;k++) acc += qS[k]*Wx[k*32+tid];
    const float* s1 = &seq1hot[bid*21];
    for (int k=0;k<21;k++) acc += s1[k]*Wx[(64+k)*32+tid];
    float s = wred32(acc), s2 = wred32(acc*acc);
    float mu = s*(1.f/32.f), var = s2*(1.f/32.f)-mu*mu;
    float v = (acc-mu)*rsqrtf(var+EPSLN)*g_node[tid] + b_node[tid];
    node[bid*32+tid] = v;
    nodeS[tid] = v;
  }
  __syncthreads();
  if (tid<16){
    float acc = b0[tid];
    for (int k=0;k<32;k++) acc += nodeS[k]*W0[(32+k)*16+tid];
    m0bG[bid*16+tid] = acc;
  }

  // --- Phase 2: distances, exact stable top-k rank, compaction (tid<256, thread=j) ---
  const bool act = tid < 256;
  const int i = bid & 255;
  const int j = tid;
  float D = 0.f;
  if (act){
    const float cax = xyz[(bid*3+1)*3+0];
    const float cay = xyz[(bid*3+1)*3+1];
    const float caz = xyz[(bid*3+1)*3+2];
    const int jb = (b<<8)+j;
    float dx = xyz[(jb*3+1)*3+0]-cax;
    float dy = xyz[(jb*3+1)*3+1]-cay;
    float dz = xyz[(jb*3+1)*3+2]-caz;
    D = sqrtf(dx*dx+dy*dy+dz*dz) + (i==j ? 999.9f : 0.f);
  }
  __syncthreads();
  if (act) Dv[j] = D;
  __syncthreads();
  if (act){
    int rank = 0;
    for (int j2=0;j2<256;j2+=4){
      const float4 dv = *(const float4*)&Dv[j2];
      rank += (dv.x < D || (dv.x == D && (j2+0) < j)) ? 1 : 0;
      rank += (dv.y < D || (dv.y == D && (j2+1) < j)) ? 1 : 0;
      rank += (dv.z < D || (dv.z == D && (j2+2) < j)) ? 1 : 0;
      rank += (dv.w < D || (dv.w == D && (j2+3) < j)) ? 1 : 0;
    }
    int K = topk[0];
    if (K<=0 || K>256){
      float f = ((const float*)topk)[0];
      K = (f>=1.f && f<=256.f) ? (int)f : 64;
    }
    const int jb = (b<<8)+j;
    const int sep = abs(idxp[jb] - idxp[bid]);
    const bool m = (rank < K) || (i!=j && sep < KMINC);
    unsigned long long bal = __ballot(m);
    const int l6 = j & 63, wv = j >> 6;
    const int pre = __popcll(bal & ((1ull<<l6)-1ull));
    if (l6==0) wsum[wv] = __popcll(bal);
    __syncthreads();
    int off = 0;
    for (int w2=0;w2<wv;w2++) off += wsum[w2];
    if (m) jlist[bid*96 + off + pre] = j;
    if (j==0) cnt[bid] = wsum[0]+wsum[1]+wsum[2]+wsum[3];
  } else {
    __syncthreads();
  }
}

// ---------------- Kernel C: wave-per-slice gathered pipeline, b128 LDS ----------------
// grid = 512*SLI/4 (1280), block = 256 = 4 independent waves; wave = one 8-row slice.
// All GEMV LDS reads are 16B (uint4): q-blocked weights (1 b128/iter, conflict-free
// 16B-stride) + 16B broadcast operand rows. ~170 ds ops/wave vs ~600 b32 before.
__global__ __launch_bounds__(256) void k_main(
    const float* __restrict__ pair, const float* __restrict__ xyz,
    const float* __restrict__ g_pair, const float* __restrict__ b_pair,
    const float* __restrict__ be, const float* __restrict__ g_edge,
    const float* __restrict__ b_edge, const float* __restrict__ ba,
    const float* __restrict__ node, const int* __restrict__ cnt,
    const int* __restrict__ jlist, const float* __restrict__ m0bG,
    const unsigned* __restrict__ packW, float* __restrict__ part)
{
  const int tid = threadIdx.x;
  const int w  = tid >> 6;          // wave 0..3
  const int wl = tid & 63;          // lane in wave
  const int r  = (tid >> 5) & 1;    // group in wave
  const int t  = tid & 31;          // lane in group

  __shared__ alignas(16) unsigned WeL[2048];        // 8 KB q-blocked
  __shared__ alignas(16) unsigned WaL[512];         // 2 KB
  __shared__ alignas(16) unsigned W0L[768];         // 3 KB
  __shared__ alignas(16) unsigned WcL[192];         // 768 B
  __shared__ float waD[32];
  __shared__ float beS[32], geS[32], beeS[32], baS[32];
  __shared__ alignas(16) _Float16 pnH[32][128];     // 8 KB
  __shared__ alignas(16) _Float16 edH[32][32];      // 2 KB
  __shared__ alignas(16) _Float16 aH [32][32];      // 2 KB
  __shared__ alignas(16) _Float16 ndH[32][32];      // 2 KB
  __shared__ float cS[32*12];
  __shared__ float xjS[32][9];
  __shared__ float geoS[32][4];

  for (int i2=tid;i2<2048;i2+=256) WeL[i2] = packW[i2];
  for (int i2=tid;i2<512; i2+=256) WaL[i2] = packW[2048+i2];
  for (int i2=tid;i2<768; i2+=256) W0L[i2] = packW[2560+i2];
  if (tid<192) WcL[tid] = packW[3328+tid];
  if (tid<32){
    waD[tid] = ((const float*)packW)[3520+tid];
    beS[tid]=be[tid]; geS[tid]=g_edge[tid]; beeS[tid]=b_edge[tid]; baS[tid]=ba[tid];
  }
  __syncthreads();        // the ONLY block-wide barrier

  const int s    = blockIdx.x*4 + w;   // slice id
  const int item = s / SLI;            // (b,i)
  const int sl   = s - item*SLI;
  const int b    = item >> 8;
  const int n    = cnt[item];
  const int row0 = sl*8;
  const int wrow = w*8;

  float stA = 0.f;
  float ofA = 0.f;

  if (row0 < n){
    const float cax = xyz[(item*3+1)*3+0];
    const float cay = xyz[(item*3+1)*3+1];
    const float caz = xyz[(item*3+1)*3+2];
    bool vals[4];
    // ---- stage 4 rows per group ----
    {
      const float4 gp4 = *(const float4*)&g_pair[4*t];
      const float4 bp4 = *(const float4*)&b_pair[4*t];
      #pragma unroll
      for (int jc=0;jc<4;jc++){
        const int slot = row0 + r*4 + jc;
        vals[jc] = slot < n;
        const int jj = vals[jc] ? jlist[item*96 + slot] : 0;
        const int row = wrow + r*4 + jc;
        const float* prow = &pair[((long)item*256 + jj)*128];
        const float4 pv4 = *(const float4*)&prow[4*t];
        float sm  = wred32(pv4.x+pv4.y+pv4.z+pv4.w);
        float sm2 = wred32(pv4.x*pv4.x+pv4.y*pv4.y+pv4.z*pv4.z+pv4.w*pv4.w);
        float mu = sm*(1.f/128.f);
        float var = sm2*(1.f/128.f)-mu*mu;
        float rs = rsqrtf(var+EPSLN);
        h4 o;
        o[0]=(_Float16)((pv4.x-mu)*rs*gp4.x+bp4.x);
        o[1]=(_Float16)((pv4.y-mu)*rs*gp4.y+bp4.y);
        o[2]=(_Float16)((pv4.z-mu)*rs*gp4.z+bp4.z);
        o[3]=(_Float16)((pv4.w-mu)*rs*gp4.w+bp4.w);
        *(h4*)&pnH[row][4*t] = o;
        const int jb=(b<<8)+jj;
        ndH[row][t] = (_Float16)node[jb*32+t];
        if (t<9) xjS[row][t] = xyz[(size_t)jb*9 + t];
        if (t==0){
          float jx = xyz[(size_t)jb*9+3]-cax;
          float jy = xyz[(size_t)jb*9+4]-cay;
          float jz = xyz[(size_t)jb*9+5]-caz;
          geoS[row][0]=jx; geoS[row][1]=jy; geoS[row][2]=jz;
          geoS[row][3]=sqrtf(jx*jx+jy*jy+jz*jz);
        }
      }
    }
    // ---- edge GEMV (128->32): 16 iters, all-b128 ----
    float ea0[4], ea1[4];
    #pragma unroll
    for (int jc=0;jc<4;jc++){ ea0[jc]=beS[t]; ea1[jc]=0.f; }
    for (int qb=0; qb<16; ++qb){
      const uint4 wv = *(const uint4*)&WeL[qb*128 + t*4];
      #pragma unroll
      for (int jc=0;jc<4;jc++){
        const uint4 pv = *(const uint4*)&pnH[wrow + r*4 + jc][8*qb];
        ea0[jc]=FDOT2(asH2(wv.y), asH2(pv.y), FDOT2(asH2(wv.x), asH2(pv.x), ea0[jc]));
        ea1[jc]=FDOT2(asH2(wv.w), asH2(pv.w), FDOT2(asH2(wv.z), asH2(pv.z), ea1[jc]));
      }
    }
    // ---- edge LN -> edH f16 ----
    #pragma unroll
    for (int jc=0;jc<4;jc++){
      float acc=ea0[jc]+ea1[jc];
      float sm=wred32(acc), sm2=wred32(acc*acc);
      float mu=sm*(1.f/32.f), var=sm2*(1.f/32.f)-mu*mu;
      edH[wrow + r*4 + jc][t] = (_Float16)((acc-mu)*rsqrtf(var+EPSLN)*geS[t]+beeS[t]);
    }
    // ---- a = relu([edge, dist] @ Wa + ba) ----
    float av[4];
    #pragma unroll
    for (int jc=0;jc<4;jc++) av[jc]=baS[t]+geoS[wrow + r*4 + jc][3]*waD[t];
    for (int qb=0; qb<4; ++qb){
      const uint4 wv = *(const uint4*)&WaL[qb*128 + t*4];
      #pragma unroll
      for (int jc=0;jc<4;jc++){
        const uint4 ev = *(const uint4*)&edH[wrow + r*4 + jc][8*qb];
        av[jc]=FDOT2(asH2(wv.w), asH2(ev.w), FDOT2(asH2(wv.z), asH2(ev.z),
                FDOT2(asH2(wv.y), asH2(ev.y), FDOT2(asH2(wv.x), asH2(ev.x), av[jc]))));
      }
    }
    #pragma unroll
    for (int jc=0;jc<4;jc++) aH[wrow + r*4 + jc][t]=(_Float16)fmaxf(av[jc],0.f);
    // ---- m0: a-part lanes t<16 (W0 blocks 0..3), node-part t>=16 (blocks 8..11) ----
    {
      const int half = t>>4, tc = t&15;
      const int wb = half ? 8 : 0;
      const float m0b = half ? 0.f : m0bG[item*16+tc];
      float m0v[4];
      #pragma unroll
      for (int jc=0;jc<4;jc++) m0v[jc]=m0b;
      for (int qb=0;qb<4;++qb){
        const uint4 wv = *(const uint4*)&W0L[(wb+qb)*64 + tc*4];
        #pragma unroll
        for (int jc=0;jc<4;jc++){
          const _Float16* opb = half ? &ndH[wrow + r*4 + jc][0] : &aH[wrow + r*4 + jc][0];
          const uint4 ov = *(const uint4*)&opb[8*qb];
          m0v[jc]=FDOT2(asH2(wv.w), asH2(ov.w), FDOT2(asH2(wv.z), asH2(ov.z),
                   FDOT2(asH2(wv.y), asH2(ov.y), FDOT2(asH2(wv.x), asH2(ov.x), m0v[jc]))));
        }
      }
      #pragma unroll
      for (int jc=0;jc<4;jc++){
        float tot = m0v[jc] + __shfl_xor(m0v[jc], 16);
        if (t<16 && vals[jc]) stA += fmaxf(tot, 0.f);
      }
    }
    // ---- c1/c2 from a: lanes t<12 k-rows 0..15 (blocks 0..1), lanes 12..23 k 16..31 (blocks 2..3) ----
    {
      const bool up = (t>=12 && t<24);
      const int tc12 = up ? t-12 : (t<12 ? t : 0);
      const int wb = up ? 2 : 0;
      const int koff = up ? 16 : 0;
      float cv[4]={0.f,0.f,0.f,0.f};
      for (int qb=0;qb<2;++qb){
        const uint4 wv = *(const uint4*)&WcL[(wb+qb)*48 + tc12*4];
        #pragma unroll
        for (int jc=0;jc<4;jc++){
          const uint4 av2 = *(const uint4*)&aH[wrow + r*4 + jc][koff + 8*qb];
          cv[jc]=FDOT2(asH2(wv.w), asH2(av2.w), FDOT2(asH2(wv.z), asH2(av2.z),
                  FDOT2(asH2(wv.y), asH2(av2.y), FDOT2(asH2(wv.x), asH2(av2.x), cv[jc]))));
        }
      }
      #pragma unroll
      for (int jc=0;jc<4;jc++){
        const int src = (t<12) ? t+12 : (up ? t-12 : t);
        float other = __shfl(cv[jc], src, 32);
        if (t<12) cS[(wrow + r*4 + jc)*12+t] = cv[jc]+other;
      }
    }
    // ---- offset accumulation (t<9) ----
    if (t<9){
      const int o=t/3, x=t-o*3;
      #pragma unroll
      for (int jc=0;jc<4;jc++){
        if (!vals[jc]) continue;
        const int row = wrow + r*4 + jc;
        const float dj = geoS[row][3];
        const float dh = geoS[row][x]/(dj+1e-8f);
        const float* cr = &cS[row*12];
        float val = cr[o]*dh;
        const float caxj = xjS[row][3+x];
        #pragma unroll
        for (int c=0;c<3;c++){
          val += cr[3+o*3+c]*(xjS[row][c*3+x]-caxj);
        }
        ofA += val;
      }
    }
  }

  stA += __shfl_xor(stA, 32);
  ofA += __shfl_xor(ofA, 32);
  if (wl < 16) part[s*28 + wl] = stA;
  if (wl < 9)  part[s*28 + 16 + wl] = ofA;
}

// ---------------- Kernel F: combine partials, scale by deg, form xyz_new ----------------
// grid = B*L (512), block = 64
__global__ __launch_bounds__(64) void k_fin(
    const float* __restrict__ xyz, const int* __restrict__ cnt,
    const float* __restrict__ part, float* __restrict__ out)
{
  const int bid = blockIdx.x;
  const int t = threadIdx.x;
  __shared__ float offF[9];
  const int n = cnt[bid];
  const float invd = 1.f/fmaxf((float)n,1.f);
  if (t<16){
    float s=0.f;
    #pragma unroll
    for (int k2=0;k2<SLI;k2++) s += part[(bid*SLI+k2)*28 + t];
    out[4608 + bid*16 + t] = s*invd;           // state
  } else if (t<25){
    float s=0.f;
    #pragma unroll
    for (int k2=0;k2<SLI;k2++) s += part[(bid*SLI+k2)*28 + t];
    offF[t-16] = s*invd;
  }
  __syncthreads();
  if (t<9){
    const int o=t/3, x=t-o*3;
    const float cac = xyz[(bid*3+1)*3+x];
    const float CA = cac + offF[3+x];          // offset[:,:,1]
    const float v = (o==1)? CA : (CA + offF[o*3+x]);
    out[bid*9 + t] = v;                        // xyz_new
  }
}

extern "C" void kernel_launch(void* const* d_in, const int* in_sizes, int n_in,
                              void* d_out, int out_size, void* d_ws, size_t ws_size,
                              hipStream_t stream)
{
  const float* msa     = (const float*)d_in[0];
  const float* pair    = (const float*)d_in[1];
  const float* xyz     = (const float*)d_in[2];
  const float* seq1hot = (const float*)d_in[3];
  const float* g_msa   = (const float*)d_in[4];
  const float* b_msa   = (const float*)d_in[5];
  const float* g_pair  = (const float*)d_in[6];
  const float* b_pair  = (const float*)d_in[7];
  const float* Wq      = (const float*)d_in[8];
  const float* bq      = (const float*)d_in[9];
  const float* Wk      = (const float*)d_in[10];
  const float* bk      = (const float*)d_in[11];
  const float* Wx      = (const float*)d_in[12];
  const float* bx      = (const float*)d_in[13];
  const float* g_node  = (const float*)d_in[14];
  const float* b_node  = (const float*)d_in[15];
  const float* We      = (const float*)d_in[16];
  const float* be      = (const float*)d_in[17];
  const float* g_edge  = (const float*)d_in[18];
  const float* b_edge  = (const float*)d_in[19];
  const float* Wa      = (const float*)d_in[20];
  const float* ba      = (const float*)d_in[21];
  const float* W0      = (const float*)d_in[22];
  const float* b0      = (const float*)d_in[23];
  const float* Wc1     = (const float*)d_in[24];
  const float* Wc2     = (const float*)d_in[25];
  const int*   idx     = (const int*)d_in[26];
  const int*   topk    = (const int*)d_in[27];
  float* out = (float*)d_out;

  float* wsf = (float*)d_ws;
  float*    node  = wsf + WS_NODE;
  int*      cnt   = (int*)(wsf + WS_CNT);
  int*      jlist = (int*)(wsf + WS_JLIST);
  float*    m0bG  = wsf + WS_M0B;
  float*    partb = wsf + WS_PART;
  unsigned* packW = (unsigned*)(wsf + WS_PACKW);

  k_prep<<<512, 512, 0, stream>>>(msa, seq1hot, xyz, idx, topk, g_msa, b_msa,
                                  Wq, bq, Wk, bk, Wx, bx, g_node, b_node,
                                  We, Wa, W0, b0, Wc1, Wc2,
                                  node, cnt, jlist, m0bG, packW);
  k_main<<<512*SLI/4, 256, 0, stream>>>(pair, xyz, g_pair, b_pair, be, g_edge,
                                        b_edge, ba, node, cnt, jlist, m0bG,
                                        packW, partb);
  k_fin<<<512, 64, 0, stream>>>(xyz, cnt, partb, out);
}